// Round 3
// baseline (358.649 us; speedup 1.0000x reference)
//
#include <hip/hip_runtime.h>

// Workspace layout (floats), written by prep_kernel each call.
// All weights pre-transposed to column-major so the inner "broadcast h_j,
// FMA into a[0..31]" form reads contiguous wave-uniform columns (-> s_load),
// and so adjacent output indices (k for W_hh, o for W1/W2/W3) form 8-byte
// pairs for packed v_pk_fma_f32.
// W_ih, (b_ih+b_hh), W_hh are pre-scaled by K = 2*log2(e) so that
// tanh(a) = 1 - 2/(1 + exp2(K*a)) needs no per-element scaling.
#define OFF_WIH 0      // 32   : W_ih[k]*K
#define OFF_C   32     // 32   : (b_ih[k]+b_hh[k])*K
#define OFF_WHH 64     // 1024 : col-major W_hh[k][j]*K at [j*32 + k]
#define OFF_W1  1088   // 1536 : col-major W1[o][m]    at [m*16 + o]
#define OFF_B1  2624   // 16
#define OFF_W2  2640   // 128  : col-major W2[o][k]    at [k*8 + o]
#define OFF_B2  2768   // 8
#define OFF_W3  2776   // 8
#define OFF_B3  2784   // 1

typedef float f32x2 __attribute__((ext_vector_type(2)));

__global__ void prep_kernel(const float* __restrict__ wih, const float* __restrict__ whh,
                            const float* __restrict__ bih, const float* __restrict__ bhh,
                            const float* __restrict__ w1,  const float* __restrict__ b1,
                            const float* __restrict__ w2,  const float* __restrict__ b2,
                            const float* __restrict__ w3,  const float* __restrict__ b3,
                            float* __restrict__ ws)
{
    const float K = 2.8853900817779268f; // 2*log2(e)
    const int t = threadIdx.x;
    if (t < 32) {
        ws[OFF_WIH + t] = wih[t] * K;
        ws[OFF_C   + t] = (bih[t] + bhh[t]) * K;
    }
    for (int i = t; i < 1024; i += 256) {          // W_hh [32,32] row-major -> col-major, scaled
        int r = i >> 5, c = i & 31;                // whh[r][c]
        ws[OFF_WHH + c * 32 + r] = whh[i] * K;
    }
    for (int i = t; i < 1536; i += 256) {          // W1 [16,96] -> col-major
        int o = i / 96, m = i - o * 96;
        ws[OFF_W1 + m * 16 + o] = w1[i];
    }
    if (t < 16) ws[OFF_B1 + t] = b1[t];
    for (int i = t; i < 128; i += 256) {           // W2 [8,16] -> col-major
        int o = i >> 4, k = i & 15;
        ws[OFF_W2 + k * 8 + o] = w2[i];
    }
    if (t < 8) { ws[OFF_B2 + t] = b2[t]; ws[OFF_W3 + t] = w3[t]; }
    if (t == 0) ws[OFF_B3] = b3[0];
}

// tanh(a) given ap = 2*log2(e)*a:  tanh(a) = 1 - 2/(exp2(ap)+1)
__device__ __forceinline__ float tanh_fast(float ap) {
    float e = __builtin_amdgcn_exp2f(ap);
    return fmaf(-2.0f, __builtin_amdgcn_rcpf(e + 1.0f), 1.0f);
}

__device__ __forceinline__ f32x2 fma2(f32x2 a, f32x2 b, f32x2 c) {
    return __builtin_elementwise_fma(a, b, c);
}
__device__ __forceinline__ f32x2 splat2(float v) { f32x2 r; r[0] = v; r[1] = v; return r; }

// 2 batch elements per thread, paired (i, i+B/2), both streams coalesced.
// Accumulators packed along the output dim (f32x2) so the hot matvec and fc1
// loops emit v_pk_fma_f32 (VOP3P, gfx90a+): ~halves the VALU instruction
// count that R2's counters say we're bound on (VALU-busy time 167 us vs
// ~60 us of source-level math = 2.8x bloat, with VGPR_Count 124 < ~170 live
// floats -> AGPR/writelane copy spills). __launch_bounds__(256,1) gives the
// allocator the full unified budget so live state stays architectural.
__global__ __launch_bounds__(256, 1)
void rnn_mlp_kernel(const float* __restrict__ x, const float* __restrict__ ws,
                    float* __restrict__ out, int B)
{
    const int Bh  = (B + 1) >> 1;                  // elements per stream half
    const int idx = blockIdx.x * 256 + threadIdx.x;
    // Clamp instead of early-return: weight loads stay in uniform control
    // flow; tail threads duplicate a valid element (benign same-value write).
    const int i0 = (idx < Bh) ? idx : (Bh - 1);
    int i1 = i0 + Bh; if (i1 >= B) i1 = B - 1;

    const f32x2* wih2 = (const f32x2*)(ws + OFF_WIH);  // [16] pairs over k
    const f32x2* c2   = (const f32x2*)(ws + OFF_C);    // [16]
    const f32x2* whh2 = (const f32x2*)(ws + OFF_WHH);  // [j*16 + k2]
    const f32x2* w12  = (const f32x2*)(ws + OFF_W1);   // [m*8 + o2]
    const f32x2* b12  = (const f32x2*)(ws + OFF_B1);   // [8]
    const f32x2* w22  = (const f32x2*)(ws + OFF_W2);   // [k*4 + o2]
    const f32x2* b22  = (const f32x2*)(ws + OFF_B2);   // [4]
    const f32x2* w32  = (const f32x2*)(ws + OFF_W3);   // [4]

    float xa[2][3];
    #pragma unroll
    for (int t = 0; t < 3; ++t) {
        xa[0][t] = x[3 * i0 + t];
        xa[1][t] = x[3 * i1 + t];
    }

    float h[2][32];
    f32x2 a2[2][16];
    f32x2 f12[2][8];

    #pragma unroll
    for (int o2 = 0; o2 < 8; ++o2) {
        const f32x2 b = b12[o2];
        f12[0][o2] = b; f12[1][o2] = b;
    }

    #pragma unroll
    for (int t = 0; t < 3; ++t) {
        const f32x2 xv0 = splat2(xa[0][t]);
        const f32x2 xv1 = splat2(xa[1][t]);

        // pre-activation (scaled by K): a = xv*Wih' + c'  (+ Whh'*h for t>0)
        #pragma unroll
        for (int k2 = 0; k2 < 16; ++k2) {
            const f32x2 w = wih2[k2];
            const f32x2 c = c2[k2];
            a2[0][k2] = fma2(xv0, w, c);
            a2[1][k2] = fma2(xv1, w, c);
        }

        if (t > 0) {
            #pragma unroll
            for (int j = 0; j < 32; ++j) {
                const f32x2 hj0 = splat2(h[0][j]);
                const f32x2 hj1 = splat2(h[1][j]);
                #pragma unroll
                for (int k2 = 0; k2 < 16; ++k2) {
                    const f32x2 w = whh2[j * 16 + k2];
                    a2[0][k2] = fma2(hj0, w, a2[0][k2]);
                    a2[1][k2] = fma2(hj1, w, a2[1][k2]);
                }
            }
        }

        #pragma unroll
        for (int k2 = 0; k2 < 16; ++k2) {
            h[0][2 * k2 + 0] = tanh_fast(a2[0][k2][0]);
            h[0][2 * k2 + 1] = tanh_fast(a2[0][k2][1]);
            h[1][2 * k2 + 0] = tanh_fast(a2[1][k2][0]);
            h[1][2 * k2 + 1] = tanh_fast(a2[1][k2][1]);
        }

        // fc1 accumulation: f1[o] += relu(h[j]) * W1[o][t*32+j]
        #pragma unroll
        for (int j = 0; j < 32; ++j) {
            const f32x2 r0 = splat2(fmaxf(h[0][j], 0.0f));
            const f32x2 r1 = splat2(fmaxf(h[1][j], 0.0f));
            #pragma unroll
            for (int o2 = 0; o2 < 8; ++o2) {
                const f32x2 w = w12[(t * 32 + j) * 8 + o2];
                f12[0][o2] = fma2(r0, w, f12[0][o2]);
                f12[1][o2] = fma2(r1, w, f12[1][o2]);
            }
        }
    }

    // fc2 (16 -> 8) + relu
    f32x2 g2[2][4];
    #pragma unroll
    for (int o2 = 0; o2 < 4; ++o2) {
        const f32x2 b = b22[o2];
        g2[0][o2] = b; g2[1][o2] = b;
    }
    #pragma unroll
    for (int k = 0; k < 16; ++k) {
        const f32x2 v0 = splat2(f12[0][k >> 1][k & 1]);
        const f32x2 v1 = splat2(f12[1][k >> 1][k & 1]);
        #pragma unroll
        for (int o2 = 0; o2 < 4; ++o2) {
            const f32x2 w = w22[k * 4 + o2];
            g2[0][o2] = fma2(v0, w, g2[0][o2]);
            g2[1][o2] = fma2(v1, w, g2[1][o2]);
        }
    }

    // fc3 (8 -> 1): packed partial sums, horizontal add at the end
    const f32x2 z = splat2(0.0f);
    f32x2 y0p = z, y1p = z;
    #pragma unroll
    for (int o2 = 0; o2 < 4; ++o2) {
        const f32x2 w = w32[o2];
        y0p = fma2(__builtin_elementwise_max(g2[0][o2], z), w, y0p);
        y1p = fma2(__builtin_elementwise_max(g2[1][o2], z), w, y1p);
    }
    const float b3v = ws[OFF_B3];
    out[i0] = y0p[0] + y0p[1] + b3v;
    out[i1] = y1p[0] + y1p[1] + b3v;
}

extern "C" void kernel_launch(void* const* d_in, const int* in_sizes, int n_in,
                              void* d_out, int out_size, void* d_ws, size_t ws_size,
                              hipStream_t stream)
{
    const float* x   = (const float*)d_in[0];
    const float* wih = (const float*)d_in[1];
    const float* whh = (const float*)d_in[2];
    const float* bih = (const float*)d_in[3];
    const float* bhh = (const float*)d_in[4];
    const float* w1  = (const float*)d_in[5];
    const float* b1  = (const float*)d_in[6];
    const float* w2  = (const float*)d_in[7];
    const float* b2  = (const float*)d_in[8];
    const float* w3  = (const float*)d_in[9];
    const float* b3  = (const float*)d_in[10];
    float* out = (float*)d_out;
    float* ws  = (float*)d_ws;

    const int B = in_sizes[0] / 3;

    prep_kernel<<<1, 256, 0, stream>>>(wih, whh, bih, bhh, w1, b1, w2, b2, w3, b3, ws);
    const int Bh = (B + 1) >> 1;
    rnn_mlp_kernel<<<(Bh + 255) / 256, 256, 0, stream>>>(x, ws, out, B);
}

// Round 4
// 354.819 us; speedup vs baseline: 1.0108x; 1.0108x over previous
//
#include <hip/hip_runtime.h>

// Workspace layout (floats), written by prep_kernel each call.
// All weights pre-transposed to column-major so the inner "broadcast h_j,
// FMA into a[0..31]" form reads contiguous wave-uniform columns.
// W_ih, (b_ih+b_hh), W_hh are pre-scaled by K = 2*log2(e) so that
// tanh(a) = 1 - 2/(1 + exp2(K*a)) needs no per-element scaling.
#define OFF_WIH 0      // 32   : W_ih[k]*K
#define OFF_C   32     // 32   : (b_ih[k]+b_hh[k])*K
#define OFF_WHH 64     // 1024 : col-major W_hh[k][j]*K at [j*32 + k]
#define OFF_W1  1088   // 1536 : col-major W1[o][m]    at [m*16 + o]
#define OFF_B1  2624   // 16
#define OFF_W2  2640   // 128  : col-major W2[o][k]    at [k*8 + o]
#define OFF_B2  2768   // 8
#define OFF_W3  2776   // 8
#define OFF_B3  2784   // 1

__global__ void prep_kernel(const float* __restrict__ wih, const float* __restrict__ whh,
                            const float* __restrict__ bih, const float* __restrict__ bhh,
                            const float* __restrict__ w1,  const float* __restrict__ b1,
                            const float* __restrict__ w2,  const float* __restrict__ b2,
                            const float* __restrict__ w3,  const float* __restrict__ b3,
                            float* __restrict__ ws)
{
    const float K = 2.8853900817779268f; // 2*log2(e)
    const int t = threadIdx.x;
    if (t < 32) {
        ws[OFF_WIH + t] = wih[t] * K;
        ws[OFF_C   + t] = (bih[t] + bhh[t]) * K;
    }
    for (int i = t; i < 1024; i += 256) {          // W_hh [32,32] row-major -> col-major, scaled
        int r = i >> 5, c = i & 31;                // whh[r][c]
        ws[OFF_WHH + c * 32 + r] = whh[i] * K;
    }
    for (int i = t; i < 1536; i += 256) {          // W1 [16,96] -> col-major
        int o = i / 96, m = i - o * 96;
        ws[OFF_W1 + m * 16 + o] = w1[i];
    }
    if (t < 16) ws[OFF_B1 + t] = b1[t];
    for (int i = t; i < 128; i += 256) {           // W2 [8,16] -> col-major
        int o = i >> 4, k = i & 15;
        ws[OFF_W2 + k * 8 + o] = w2[i];
    }
    if (t < 8) { ws[OFF_B2 + t] = b2[t]; ws[OFF_W3 + t] = w3[t]; }
    if (t == 0) ws[OFF_B3] = b3[0];
}

// tanh(a) given ap = 2*log2(e)*a:  tanh(a) = 1 - 2/(exp2(ap)+1)
__device__ __forceinline__ float tanh_fast(float ap) {
    float e = __builtin_amdgcn_exp2f(ap);
    return fmaf(-2.0f, __builtin_amdgcn_rcpf(e + 1.0f), 1.0f);
}

// 4 batch elements per thread at (i, i+B/4, i+2B/4, i+3B/4): all four global
// streams stay coalesced, and every wave-uniform weight fetch feeds FOUR fmas.
// R1->R2 proved weight-stream amortization is the lever (2 elems: 522->214us,
// matching the streams model); R3 proved f32x2 packing is neutral (VALU-busy
// time unchanged) and that losing resident waves costs latency hiding -- so
// each wave now carries 4 independent dependency chains to self-hide latency
// even at ~1 wave/SIMD. Scalar fmas only (packing reverted).
// Live state 4*(32+32+16)=320 floats -> needs the full 512-reg budget:
// __launch_bounds__(256,1). No scratch expected (WRITE_SIZE must stay 4MB).
#define NELEM 4
__global__ __launch_bounds__(256, 1)
void rnn_mlp_kernel(const float* __restrict__ x, const float* __restrict__ ws,
                    float* __restrict__ out, int B)
{
    const int Bq  = B >> 2;                        // B is a multiple of 4*256 here
    const int idx = blockIdx.x * 256 + threadIdx.x;
    // Clamp instead of early-return: weight loads stay in uniform control
    // flow; tail threads duplicate a valid element (benign same-value write).
    const int i0 = (idx < Bq) ? idx : (Bq - 1);

    int ei[NELEM];
    #pragma unroll
    for (int e = 0; e < NELEM; ++e) {
        int v = i0 + e * Bq;
        ei[e] = (v < B) ? v : (B - 1);
    }

    float xa[NELEM][3];
    #pragma unroll
    for (int e = 0; e < NELEM; ++e) {
        #pragma unroll
        for (int t = 0; t < 3; ++t) xa[e][t] = x[3 * ei[e] + t];
    }

    float h[NELEM][32];
    float a[NELEM][32];
    float f1[NELEM][16];

    #pragma unroll
    for (int o = 0; o < 16; ++o) {
        const float b = ws[OFF_B1 + o];
        #pragma unroll
        for (int e = 0; e < NELEM; ++e) f1[e][o] = b;
    }

    #pragma unroll
    for (int t = 0; t < 3; ++t) {
        // pre-activation (scaled by K): a = xv*Wih' + c'  (+ Whh'*h for t>0)
        #pragma unroll
        for (int k = 0; k < 32; ++k) {
            const float w = ws[OFF_WIH + k];
            const float c = ws[OFF_C + k];
            #pragma unroll
            for (int e = 0; e < NELEM; ++e) a[e][k] = fmaf(xa[e][t], w, c);
        }

        if (t > 0) {
            #pragma unroll
            for (int j = 0; j < 32; ++j) {
                #pragma unroll
                for (int k = 0; k < 32; ++k) {
                    const float w = ws[OFF_WHH + j * 32 + k];
                    #pragma unroll
                    for (int e = 0; e < NELEM; ++e)
                        a[e][k] = fmaf(h[e][j], w, a[e][k]);
                }
            }
        }

        #pragma unroll
        for (int k = 0; k < 32; ++k) {
            #pragma unroll
            for (int e = 0; e < NELEM; ++e) h[e][k] = tanh_fast(a[e][k]);
        }

        // fc1 accumulation: f1[o] += relu(h[j]) * W1[o][t*32+j]
        #pragma unroll
        for (int j = 0; j < 32; ++j) {
            float r[NELEM];
            #pragma unroll
            for (int e = 0; e < NELEM; ++e) r[e] = fmaxf(h[e][j], 0.0f);
            #pragma unroll
            for (int o = 0; o < 16; ++o) {
                const float w = ws[OFF_W1 + (t * 32 + j) * 16 + o];
                #pragma unroll
                for (int e = 0; e < NELEM; ++e) f1[e][o] = fmaf(r[e], w, f1[e][o]);
            }
        }
    }

    // fc2 (16 -> 8) + relu
    float g[NELEM][8];
    #pragma unroll
    for (int o = 0; o < 8; ++o) {
        const float b = ws[OFF_B2 + o];
        #pragma unroll
        for (int e = 0; e < NELEM; ++e) g[e][o] = b;
    }
    #pragma unroll
    for (int k = 0; k < 16; ++k) {
        #pragma unroll
        for (int o = 0; o < 8; ++o) {
            const float w = ws[OFF_W2 + k * 8 + o];
            #pragma unroll
            for (int e = 0; e < NELEM; ++e) g[e][o] = fmaf(f1[e][k], w, g[e][o]);
        }
    }

    // fc3 (8 -> 1)
    float y[NELEM];
    #pragma unroll
    for (int e = 0; e < NELEM; ++e) y[e] = ws[OFF_B3];
    #pragma unroll
    for (int o = 0; o < 8; ++o) {
        const float w = ws[OFF_W3 + o];
        #pragma unroll
        for (int e = 0; e < NELEM; ++e)
            y[e] = fmaf(fmaxf(g[e][o], 0.0f), w, y[e]);
    }

    #pragma unroll
    for (int e = 0; e < NELEM; ++e) out[ei[e]] = y[e];
}

extern "C" void kernel_launch(void* const* d_in, const int* in_sizes, int n_in,
                              void* d_out, int out_size, void* d_ws, size_t ws_size,
                              hipStream_t stream)
{
    const float* x   = (const float*)d_in[0];
    const float* wih = (const float*)d_in[1];
    const float* whh = (const float*)d_in[2];
    const float* bih = (const float*)d_in[3];
    const float* bhh = (const float*)d_in[4];
    const float* w1  = (const float*)d_in[5];
    const float* b1  = (const float*)d_in[6];
    const float* w2  = (const float*)d_in[7];
    const float* b2  = (const float*)d_in[8];
    const float* w3  = (const float*)d_in[9];
    const float* b3  = (const float*)d_in[10];
    float* out = (float*)d_out;
    float* ws  = (float*)d_ws;

    const int B = in_sizes[0] / 3;

    prep_kernel<<<1, 256, 0, stream>>>(wih, whh, bih, bhh, w1, b1, w2, b2, w3, b3, ws);
    const int Bq = B >> 2;
    rnn_mlp_kernel<<<(Bq + 255) / 256, 256, 0, stream>>>(x, ws, out, B);
}

// Round 6
// 147.637 us; speedup vs baseline: 2.4293x; 2.4033x over previous
//
#include <hip/hip_runtime.h>

typedef short bf16x8 __attribute__((ext_vector_type(8)));   // 8 bf16 = 4 VGPRs
typedef float f32x16 __attribute__((ext_vector_type(16)));

// pack two fp32 into (bf16(b)<<16)|bf16(a) by truncation; paired with
// lo = x - trunc_bf16(x), the hi+lo split is exact to ~2^-17 rel.
__device__ __forceinline__ unsigned pack_hi(float a, float b) {
    return (__float_as_uint(b) & 0xffff0000u) | (__float_as_uint(a) >> 16);
}
__device__ __forceinline__ float lo_part(float v) {
    return v - __uint_as_float(__float_as_uint(v) & 0xffff0000u);
}

// tanh(a) given ap = 2*log2(e)*a:  tanh(a) = 1 - 2/(exp2(ap)+1)
__device__ __forceinline__ float tanh_fast(float ap) {
    float e = __builtin_amdgcn_exp2f(ap);
    return fmaf(-2.0f, __builtin_amdgcn_rcpf(e + 1.0f), 1.0f);
}

union FU { unsigned u[4]; bf16x8 v; };

// One wave = 32 batch elements (N-dim of mfma_f32_32x32x16_bf16).
// Weight A-fragments are built IN-REGISTER from the raw weight arrays once
// per wave (no workspace dependency -- R5's expanded workspace tables were an
// unproven-size risk). Operand k-layout corrected per m162's measured
// tr_b16->MFMA feed: elem i of lane l covers k = (i&3) + 8*(i>>2) + 4*(l>>5)
// (two old-K blocks concatenated), NOT a contiguous 8-run.
// Activations: acc-layout f32 -> wave-private LDS slice -> B-frags
// (split bf16, 4-product per matvec for ~fp32 accuracy). No barriers.
// fc2/fc3 on VALU after an LDS half-exchange; weights read wave-uniform.
__global__ __launch_bounds__(256, 2)
void rnn_mlp_kernel(const float* __restrict__ x,
                    const float* __restrict__ wih, const float* __restrict__ whh,
                    const float* __restrict__ bih, const float* __restrict__ bhh,
                    const float* __restrict__ w1,  const float* __restrict__ b1,
                    const float* __restrict__ w2,  const float* __restrict__ b2,
                    const float* __restrict__ w3,  const float* __restrict__ b3,
                    float* __restrict__ out, int B)
{
    const float K = 2.8853900817779268f; // 2*log2(e): tanh(a)=1-2/(exp2(K*a)+1)
    __shared__ float lds_all[4][1024];                    // 4 KB per wave
    const int tid = threadIdx.x;
    const int wv = tid >> 6, l = tid & 63;
    const int n = l & 31, H = l >> 5;                     // n: N-col / A-row m; H: lane half
    float* myLds = lds_all[wv];

    // ---- one-time per-wave fragment build (from raw global weights) ----
    // word r holds elems 2r (lo16), 2r+1 (hi16); pair k's are consecutive:
    // j0(r) = k-base of word r = 4*H + 8*(r>>1) + 2*(r&1)   [+ c*16 globally]
    float WihS[16], CS[16];                               // rank-1 tables in C/D row layout
    #pragma unroll
    for (int r = 0; r < 16; ++r) {
        const int row = (r & 3) + 8 * (r >> 2) + 4 * H;   // verified C/D row formula
        WihS[r] = wih[row] * K;
        CS[r]   = (bih[row] + bhh[row]) * K;
    }
    FU whhF[2][2];                                        // [k-half c][hi/lo split]
    #pragma unroll
    for (int c = 0; c < 2; ++c)
        #pragma unroll
        for (int r = 0; r < 4; ++r) {
            const int j0 = c * 16 + 4 * H + 8 * (r >> 1) + 2 * (r & 1);
            const float a0 = whh[n * 32 + j0]     * K;    // h_out[m=n] += Whh[m][j]*h[j]
            const float a1 = whh[n * 32 + j0 + 1] * K;
            whhF[c][0].u[r] = pack_hi(a0, a1);
            whhF[c][1].u[r] = pack_hi(lo_part(a0), lo_part(a1));
        }
    FU w1F[3][2][2];                                      // [t][k-half c][split], rows m>=16 zero
    #pragma unroll
    for (int tt = 0; tt < 3; ++tt)
        #pragma unroll
        for (int c = 0; c < 2; ++c)
            #pragma unroll
            for (int r = 0; r < 4; ++r) {
                const int j0 = c * 16 + 4 * H + 8 * (r >> 1) + 2 * (r & 1);
                const float a0 = (n < 16) ? w1[n * 96 + tt * 32 + j0]     : 0.f;
                const float a1 = (n < 16) ? w1[n * 96 + tt * 32 + j0 + 1] : 0.f;
                w1F[tt][c][0].u[r] = pack_hi(a0, a1);
                w1F[tt][c][1].u[r] = pack_hi(lo_part(a0), lo_part(a1));
            }

    const int WSTRIDE = gridDim.x * 4 * 32;
    for (int base0 = (blockIdx.x * 4 + wv) * 32; base0 < B; base0 += WSTRIDE) {
        const int idx = base0 + n;
        const int ix  = (idx < B) ? idx : (B - 1);
        float xv[3];
        xv[0] = x[3*ix]; xv[1] = x[3*ix+1]; xv[2] = x[3*ix+2];

        f32x16 f1a, f1b;                                  // fc1 acc, two independent chains
        #pragma unroll
        for (int r = 0; r < 16; ++r) { f1a[r] = 0.f; f1b[r] = 0.f; }
        FU hF[2][2];

        #pragma unroll
        for (int t = 0; t < 3; ++t) {
            // pre-activation (K-scaled): rank-1 on VALU
            f32x16 av;
            #pragma unroll
            for (int r = 0; r < 16; ++r) av[r] = fmaf(xv[t], WihS[r], CS[r]);

            if (t > 0) {                                  // += K*Whh * h  (4-product split)
                f32x16 av1;
                #pragma unroll
                for (int r = 0; r < 16; ++r) av1[r] = 0.f;
                av  = __builtin_amdgcn_mfma_f32_32x32x16_bf16(whhF[0][0].v, hF[0][0].v, av,  0,0,0);
                av  = __builtin_amdgcn_mfma_f32_32x32x16_bf16(whhF[0][0].v, hF[0][1].v, av,  0,0,0);
                av  = __builtin_amdgcn_mfma_f32_32x32x16_bf16(whhF[0][1].v, hF[0][0].v, av,  0,0,0);
                av  = __builtin_amdgcn_mfma_f32_32x32x16_bf16(whhF[0][1].v, hF[0][1].v, av,  0,0,0);
                av1 = __builtin_amdgcn_mfma_f32_32x32x16_bf16(whhF[1][0].v, hF[1][0].v, av1, 0,0,0);
                av1 = __builtin_amdgcn_mfma_f32_32x32x16_bf16(whhF[1][0].v, hF[1][1].v, av1, 0,0,0);
                av1 = __builtin_amdgcn_mfma_f32_32x32x16_bf16(whhF[1][1].v, hF[1][0].v, av1, 0,0,0);
                av1 = __builtin_amdgcn_mfma_f32_32x32x16_bf16(whhF[1][1].v, hF[1][1].v, av1, 0,0,0);
                #pragma unroll
                for (int r = 0; r < 16; ++r) av[r] += av1[r];
            }

            // tanh, write h to LDS at (row, n); row=(r&3)+8*(r>>2)+4*H.
            #pragma unroll
            for (int r = 0; r < 16; ++r)
                myLds[((r&3) + 8*(r>>2))*32 + H*128 + n] = tanh_fast(av[r]);

            // read the 16 j-rows this lane's B-frag needs (corrected mapping):
            // elem i of half c  <->  j = c*16 + 4*H + (i&3) + 8*(i>>2)
            float vr[2][8];
            #pragma unroll
            for (int c = 0; c < 2; ++c)
                #pragma unroll
                for (int i = 0; i < 8; ++i)
                    vr[c][i] = myLds[(c*16 + 4*H + (i&3) + 8*(i>>2))*32 + n];

            // build B-frags: hF (next matvec), rF = relu(h) (fc1)
            FU rF[2][2];
            #pragma unroll
            for (int c = 0; c < 2; ++c) {
                #pragma unroll
                for (int q = 0; q < 4; ++q) {
                    const float v0 = vr[c][2*q], v1 = vr[c][2*q+1];
                    if (t < 2) {
                        hF[c][0].u[q] = pack_hi(v0, v1);
                        hF[c][1].u[q] = pack_hi(lo_part(v0), lo_part(v1));
                    }
                    const float r0 = fmaxf(v0, 0.f), r1 = fmaxf(v1, 0.f);
                    rF[c][0].u[q] = pack_hi(r0, r1);
                    rF[c][1].u[q] = pack_hi(lo_part(r0), lo_part(r1));
                }
            }

            // fc1 += W1_t * relu(h): two independent chains (c=0 -> f1a, c=1 -> f1b)
            f1a = __builtin_amdgcn_mfma_f32_32x32x16_bf16(w1F[t][0][0].v, rF[0][0].v, f1a, 0,0,0);
            f1a = __builtin_amdgcn_mfma_f32_32x32x16_bf16(w1F[t][0][0].v, rF[0][1].v, f1a, 0,0,0);
            f1a = __builtin_amdgcn_mfma_f32_32x32x16_bf16(w1F[t][0][1].v, rF[0][0].v, f1a, 0,0,0);
            f1a = __builtin_amdgcn_mfma_f32_32x32x16_bf16(w1F[t][0][1].v, rF[0][1].v, f1a, 0,0,0);
            f1b = __builtin_amdgcn_mfma_f32_32x32x16_bf16(w1F[t][1][0].v, rF[1][0].v, f1b, 0,0,0);
            f1b = __builtin_amdgcn_mfma_f32_32x32x16_bf16(w1F[t][1][0].v, rF[1][1].v, f1b, 0,0,0);
            f1b = __builtin_amdgcn_mfma_f32_32x32x16_bf16(w1F[t][1][1].v, rF[1][0].v, f1b, 0,0,0);
            f1b = __builtin_amdgcn_mfma_f32_32x32x16_bf16(w1F[t][1][1].v, rF[1][1].v, f1b, 0,0,0);
        }

        // fc2/fc3: exchange f1 halves through LDS, then scalar math.
        // f1 rows 0..15 live in acc regs 0..7 (rows>=16 are zero-padded W1).
        #pragma unroll
        for (int r = 0; r < 8; ++r)
            myLds[((r&3) + 8*(r>>2) + 4*H)*32 + n] = f1a[r] + f1b[r];
        float g[8];
        #pragma unroll
        for (int o = 0; o < 8; ++o) g[o] = b2[o];
        #pragma unroll
        for (int k = 0; k < 16; ++k) {
            const float v = myLds[k*32 + n] + b1[k];
            #pragma unroll
            for (int o = 0; o < 8; ++o) g[o] = fmaf(v, w2[o*16 + k], g[o]);
        }
        float y = b3[0];
        #pragma unroll
        for (int o = 0; o < 8; ++o) y = fmaf(fmaxf(g[o], 0.f), w3[o], y);
        if (H == 0 && idx < B) out[idx] = y;
    }
}

extern "C" void kernel_launch(void* const* d_in, const int* in_sizes, int n_in,
                              void* d_out, int out_size, void* d_ws, size_t ws_size,
                              hipStream_t stream)
{
    const float* x   = (const float*)d_in[0];
    const float* wih = (const float*)d_in[1];
    const float* whh = (const float*)d_in[2];
    const float* bih = (const float*)d_in[3];
    const float* bhh = (const float*)d_in[4];
    const float* w1  = (const float*)d_in[5];
    const float* b1  = (const float*)d_in[6];
    const float* w2  = (const float*)d_in[7];
    const float* b2  = (const float*)d_in[8];
    const float* w3  = (const float*)d_in[9];
    const float* b3  = (const float*)d_in[10];
    float* out = (float*)d_out;

    const int B = in_sizes[0] / 3;

    int blocks = (B + 127) / 128;                 // 4 waves/block, 32 elem/wave/iter
    if (blocks > 1024) blocks = 1024;             // grid-stride beyond this
    rnn_mlp_kernel<<<blocks, 256, 0, stream>>>(x, wih, whh, bih, bhh,
                                               w1, b1, w2, b2, w3, b3, out, B);
}